// Round 2
// baseline (311.883 us; speedup 1.0000x reference)
//
#include <hip/hip_runtime.h>
#include <hip/hip_cooperative_groups.h>

namespace cg = cooperative_groups;

#define SEQ 512
#define MD  1024
#define RK  128
#define LDA 1032   // bf16 row stride: 2064 B -> odd/16B, 2-4 way bank alias only

typedef __attribute__((ext_vector_type(8))) short  bf16x8;
typedef __attribute__((ext_vector_type(4))) float  floatx4;
typedef __attribute__((ext_vector_type(4))) unsigned short ushortx4;

// RNE f32->bf16 (truncation measured too close to absmax threshold; RNE is free)
__device__ inline unsigned short f2bf(float f) {
    union { float f; unsigned u; } v; v.f = f;
    unsigned r = v.u + 0x7fffu + ((v.u >> 16) & 1u);
    return (unsigned short)(r >> 16);
}

// Single fused kernel, 512 blocks x 256 threads (4 waves), cooperative.
// Phase A: PT[n][k] = bf16(proj[k][n])           (64 blocks' worth of threads)
// Phase B: T = bf16(batch @ proj) + row norms    (blocks 0..255, 16 rows each)
// Phase C: D = nI + nJ - 2*(T_i . T_j)           (all 512 blocks, 64x64 tiles)
// Phase C reads fragments DIRECTLY from global T (1 MB, L2-resident): no LDS
// staging, no barrier -- fewer memory instructions than the staged version.
// mode = -1: all phases + grid.sync (cooperative); mode = 0/1/2: single phase
// (fallback path when cooperative launch is unavailable).
__global__ __launch_bounds__(256, 2) void fused_all(
    const float* __restrict__ batch, const float* __restrict__ proj,
    float* __restrict__ out, unsigned short* __restrict__ T,
    float* __restrict__ Nrm, unsigned short* __restrict__ PT, int mode)
{
    __shared__ unsigned short As[16 * LDA];   // 33 KB (phase B)
    __shared__ float Np[4][16];

    const int t    = threadIdx.x;
    const int lb   = blockIdx.x;
    const int w    = t >> 6;
    const int l    = t & 63;
    const int lm   = l & 15;
    const int quad = l >> 4;

    // ---------------- Phase A: proj transpose + cvt ----------------
    if (mode < 0 || mode == 0) {
        const int gid = lb * 256 + t;
        if (gid < 16384) {                 // 128 n x 128 k-chunks
            const int n  = gid & 127;
            const int kc = (gid >> 7) * 8;
            unsigned short tmp[8];
            #pragma unroll
            for (int j = 0; j < 8; ++j)
                tmp[j] = f2bf(proj[(size_t)(kc + j) * RK + n]);
            *(bf16x8*)(PT + (size_t)n * MD + kc) = *(bf16x8*)tmp;
        }
    }
    if (mode < 0) { __threadfence(); cg::this_grid().sync(); }

    // ---------------- Phase B: T tile (16 rows) + norms ----------------
    if ((mode < 0 || mode == 1) && lb < 256) {
        const int r0 = lb * 16;            // batch viewed as 4096 x 1024

        {   // stage A tile fp32 -> bf16: row = t>>4, 8-col chunks stride 128
            const int row = t >> 4, c0 = (t & 15) * 8;
            const float* src = batch + (size_t)(r0 + row) * MD + c0;
            unsigned short* dst = As + row * LDA + c0;
            #pragma unroll
            for (int c = 0; c < 8; ++c) {
                float4 f0 = *(const float4*)(src + c * 128);
                float4 f1 = *(const float4*)(src + c * 128 + 4);
                unsigned short tmp[8];
                tmp[0] = f2bf(f0.x); tmp[1] = f2bf(f0.y);
                tmp[2] = f2bf(f0.z); tmp[3] = f2bf(f0.w);
                tmp[4] = f2bf(f1.x); tmp[5] = f2bf(f1.y);
                tmp[6] = f2bf(f1.z); tmp[7] = f2bf(f1.w);
                *(bf16x8*)(dst + c * 128) = *(bf16x8*)tmp;
            }
        }
        __syncthreads();

        // wave w owns n-cols [32w, 32w+32): two 16-n tiles, full K = 1024
        floatx4 acc0 = (floatx4){0.f, 0.f, 0.f, 0.f};
        floatx4 acc1 = (floatx4){0.f, 0.f, 0.f, 0.f};
        const unsigned short* aptr = As + lm * LDA + quad * 8;
        const unsigned short* b0 = PT + (size_t)(w * 32 + lm) * MD + quad * 8;
        const unsigned short* b1 = b0 + (size_t)16 * MD;

        #pragma unroll
        for (int s = 0; s < 32; ++s) {
            bf16x8 av = *(const bf16x8*)(aptr + s * 32);
            acc0 = __builtin_amdgcn_mfma_f32_16x16x32_bf16(
                av, *(const bf16x8*)(b0 + s * 32), acc0, 0, 0, 0);
            acc1 = __builtin_amdgcn_mfma_f32_16x16x32_bf16(
                av, *(const bf16x8*)(b1 + s * 32), acc1, 0, 0, 0);
        }

        #pragma unroll
        for (int r = 0; r < 4; ++r) {
            const float v0 = acc0[r], v1 = acc1[r];
            const int row = r0 + quad * 4 + r;
            T[(size_t)row * RK + w * 32 + lm]      = f2bf(v0);
            T[(size_t)row * RK + w * 32 + 16 + lm] = f2bf(v1);
            // norm partial over this wave's 32 n (lm bits = lane bits 0..3)
            float p = v0 * v0 + v1 * v1;
            p += __shfl_xor(p, 1, 64);
            p += __shfl_xor(p, 2, 64);
            p += __shfl_xor(p, 4, 64);
            p += __shfl_xor(p, 8, 64);
            if (lm == 0) Np[w][quad * 4 + r] = p;
        }
        __syncthreads();
        if (t < 16)
            Nrm[r0 + t] = Np[0][t] + Np[1][t] + Np[2][t] + Np[3][t];
    }
    if (mode < 0) { __threadfence(); cg::this_grid().sync(); }

    // ---------------- Phase C: distances, direct-from-global ----------------
    if (mode < 0 || mode == 2) {
        const int jt = lb & 7, it = (lb >> 3) & 7, b = lb >> 6;
        const int i0 = it * 64, j0 = jt * 64;
        const unsigned short* Tb = T + (size_t)b * SEQ * RK;

        floatx4 acc[4];
        #pragma unroll
        for (int i = 0; i < 4; ++i) acc[i] = (floatx4){0.f, 0.f, 0.f, 0.f};

        const unsigned short* ap = Tb + (size_t)(i0 + w * 16 + lm) * RK + quad * 8;
        const unsigned short* bp = Tb + (size_t)(j0 + lm) * RK + quad * 8;

        #pragma unroll
        for (int s = 0; s < 4; ++s) {
            bf16x8 av = *(const bf16x8*)(ap + s * 32);
            #pragma unroll
            for (int nt = 0; nt < 4; ++nt) {
                bf16x8 bv = *(const bf16x8*)(bp + (size_t)nt * 16 * RK + s * 32);
                acc[nt] = __builtin_amdgcn_mfma_f32_16x16x32_bf16(av, bv, acc[nt], 0, 0, 0);
            }
        }

        const float* NI = Nrm + (size_t)b * SEQ;
        float niv[4];
        #pragma unroll
        for (int r = 0; r < 4; ++r) niv[r] = NI[i0 + w * 16 + quad * 4 + r];

        float* ob = out + ((size_t)b * SEQ + (i0 + w * 16)) * SEQ + j0;
        #pragma unroll
        for (int nt = 0; nt < 4; ++nt) {
            const float njv = NI[j0 + nt * 16 + lm];
            #pragma unroll
            for (int r = 0; r < 4; ++r) {
                ob[(size_t)(quad * 4 + r) * SEQ + nt * 16 + lm] =
                    niv[r] + njv - 2.f * acc[nt][r];
            }
        }
    }
}

extern "C" void kernel_launch(void* const* d_in, const int* in_sizes, int n_in,
                              void* d_out, int out_size, void* d_ws, size_t ws_size,
                              hipStream_t stream) {
    const float* batch = (const float*)d_in[0];   // (8, 512, 1024) fp32
    const float* proj  = (const float*)d_in[1];   // (1024, 128) fp32
    float* out = (float*)d_out;                   // (8, 512, 512) fp32

    unsigned short* T   = (unsigned short*)d_ws;                              // 1 MB bf16
    float*          Nrm = (float*)((char*)d_ws + (1 << 20));                  // 16 KB fp32
    unsigned short* PT  = (unsigned short*)((char*)d_ws + (1 << 20) + (1 << 16)); // 256 KB

    int mode = -1;
    void* args[] = { (void*)&batch, (void*)&proj, (void*)&out,
                     (void*)&T, (void*)&Nrm, (void*)&PT, (void*)&mode };

    hipError_t err = hipLaunchCooperativeKernel(
        (void*)fused_all, dim3(512), dim3(256), args, 0, stream);

    if (err != hipSuccess) {
        // Fallback: same kernel, phase-gated, 3 ordinary launches.
        fused_all<<<64,  256, 0, stream>>>(batch, proj, out, T, Nrm, PT, 0);
        fused_all<<<256, 256, 0, stream>>>(batch, proj, out, T, Nrm, PT, 1);
        fused_all<<<512, 256, 0, stream>>>(batch, proj, out, T, Nrm, PT, 2);
    }
}

// Round 3
// 80.314 us; speedup vs baseline: 3.8833x; 3.8833x over previous
//
#include <hip/hip_runtime.h>

#define SEQ 512
#define MD  1024
#define RK  128
#define LDA 1032   // bf16 row stride: 2064 B -> odd/16B, 2-way bank alias only

typedef __attribute__((ext_vector_type(8))) short  bf16x8;
typedef __attribute__((ext_vector_type(4))) float  floatx4;

// RNE f32->bf16 (truncation measured too close to absmax threshold; RNE is free)
__device__ inline unsigned short f2bf(float f) {
    union { float f; unsigned u; } v; v.f = f;
    unsigned r = v.u + 0x7fffu + ((v.u >> 16) & 1u);
    return (unsigned short)(r >> 16);
}

// ---------- Kernel 1: T = bf16(batch @ proj) + row norms ----------
// 256 blocks x 512 threads (8 waves). Block owns 16 rows x full K=1024.
// N split across waves (wave w -> cols [16w,16w+16)): no cross-wave reduce.
// A tile cvt'd to bf16 once into 33 KB LDS; B-frags gathered directly from
// fp32 proj (L2-resident, 64B-coalesced per quad-group) -- no transpose
// kernel, saving one launch (launch gaps ~1.6 us each, measured r0->r1).
__global__ __launch_bounds__(512, 2) void proj_rows(
    const float* __restrict__ batch, const float* __restrict__ proj,
    unsigned short* __restrict__ T, float* __restrict__ Nrm)
{
    __shared__ unsigned short As[16 * LDA];   // 33 KB
    __shared__ float Np[8][16];

    const int t    = threadIdx.x;
    const int w    = t >> 6;
    const int l    = t & 63;
    const int lm   = l & 15;
    const int quad = l >> 4;
    const int r0   = blockIdx.x * 16;         // batch viewed as 4096 x 1024

    {   // stage A tile fp32 -> bf16: thread t -> row t>>5, 8-col chunks
        const int row = t >> 5, c0 = (t & 31) * 8;
        const float* src = batch + (size_t)(r0 + row) * MD + c0;
        unsigned short* dst = As + row * LDA + c0;
        #pragma unroll
        for (int c = 0; c < 4; ++c) {         // chunks stride 256 floats
            float4 f0 = *(const float4*)(src + c * 256);
            float4 f1 = *(const float4*)(src + c * 256 + 4);
            unsigned short tmp[8];
            tmp[0] = f2bf(f0.x); tmp[1] = f2bf(f0.y);
            tmp[2] = f2bf(f0.z); tmp[3] = f2bf(f0.w);
            tmp[4] = f2bf(f1.x); tmp[5] = f2bf(f1.y);
            tmp[6] = f2bf(f1.z); tmp[7] = f2bf(f1.w);
            *(bf16x8*)(dst + c * 256) = *(bf16x8*)tmp;
        }
    }
    __syncthreads();

    // A frag: lane holds A[m=lm][k=s*32+quad*8+j] (LDS b128)
    // B frag: lane needs proj[k][n=16w+lm], k stride RK (quad-coalesced gather)
    floatx4 acc = (floatx4){0.f, 0.f, 0.f, 0.f};
    const unsigned short* aptr = As + lm * LDA + quad * 8;
    const float* bbase = proj + (size_t)(quad * 8) * RK + w * 16 + lm;

    #pragma unroll
    for (int s = 0; s < 32; ++s) {
        bf16x8 av = *(const bf16x8*)(aptr + s * 32);
        const float* bp = bbase + (size_t)s * 32 * RK;
        unsigned short btmp[8];
        #pragma unroll
        for (int j = 0; j < 8; ++j) btmp[j] = f2bf(bp[(size_t)j * RK]);
        acc = __builtin_amdgcn_mfma_f32_16x16x32_bf16(
            av, *(bf16x8*)btmp, acc, 0, 0, 0);
    }

    // D layout: row = quad*4+r (of 16 block rows), col = 16w+lm
    #pragma unroll
    for (int r = 0; r < 4; ++r) {
        const float v = acc[r];
        T[(size_t)(r0 + quad * 4 + r) * RK + w * 16 + lm] = f2bf(v);
        // norm partial: sum v^2 over this wave's 16 cols (lm = lane bits 0..3)
        float p = v * v;
        p += __shfl_xor(p, 1, 64);
        p += __shfl_xor(p, 2, 64);
        p += __shfl_xor(p, 4, 64);
        p += __shfl_xor(p, 8, 64);
        if (lm == 0) Np[w][quad * 4 + r] = p;
    }
    __syncthreads();

    if (t < 16) {   // fold 8 wave partials -> row norm
        float s = 0.f;
        #pragma unroll
        for (int ww = 0; ww < 8; ++ww) s += Np[ww][t];
        Nrm[r0 + t] = s;
    }
}

// ---------- Kernel 2: D[b,i,j] = nI + nJ - 2 * (T_i . T_j) ----------
// 512 blocks x 256 threads (4 waves); 64x64 tile; wave w -> 16 i-rows.
// Fragments read DIRECTLY from global T (1 MB, L2-resident): no LDS, no
// barriers (correctness of this path proven in the round-2 fused kernel).
__global__ __launch_bounds__(256) void dist_mfma(
    const unsigned short* __restrict__ T, const float* __restrict__ Nrm,
    float* __restrict__ out)
{
    const int t    = threadIdx.x;
    const int w    = t >> 6;
    const int l    = t & 63;
    const int lm   = l & 15;
    const int quad = l >> 4;
    const int lb   = blockIdx.x;
    const int jt = lb & 7, it = (lb >> 3) & 7, b = lb >> 6;
    const int i0 = it * 64, j0 = jt * 64;
    const unsigned short* Tb = T + (size_t)b * SEQ * RK;

    floatx4 acc[4];
    #pragma unroll
    for (int i = 0; i < 4; ++i) acc[i] = (floatx4){0.f, 0.f, 0.f, 0.f};

    const unsigned short* ap = Tb + (size_t)(i0 + w * 16 + lm) * RK + quad * 8;
    const unsigned short* bp = Tb + (size_t)(j0 + lm) * RK + quad * 8;

    #pragma unroll
    for (int s = 0; s < 4; ++s) {
        bf16x8 av = *(const bf16x8*)(ap + s * 32);
        #pragma unroll
        for (int nt = 0; nt < 4; ++nt) {
            bf16x8 bv = *(const bf16x8*)(bp + (size_t)nt * 16 * RK + s * 32);
            acc[nt] = __builtin_amdgcn_mfma_f32_16x16x32_bf16(av, bv, acc[nt], 0, 0, 0);
        }
    }

    const float* NI = Nrm + (size_t)b * SEQ;
    float niv[4];
    #pragma unroll
    for (int r = 0; r < 4; ++r) niv[r] = NI[i0 + w * 16 + quad * 4 + r];

    float* ob = out + ((size_t)b * SEQ + (i0 + w * 16)) * SEQ + j0;
    #pragma unroll
    for (int nt = 0; nt < 4; ++nt) {
        const float njv = NI[j0 + nt * 16 + lm];
        #pragma unroll
        for (int r = 0; r < 4; ++r) {
            ob[(size_t)(quad * 4 + r) * SEQ + nt * 16 + lm] =
                niv[r] + njv - 2.f * acc[nt][r];
        }
    }
}

extern "C" void kernel_launch(void* const* d_in, const int* in_sizes, int n_in,
                              void* d_out, int out_size, void* d_ws, size_t ws_size,
                              hipStream_t stream) {
    const float* batch = (const float*)d_in[0];   // (8, 512, 1024) fp32
    const float* proj  = (const float*)d_in[1];   // (1024, 128) fp32
    float* out = (float*)d_out;                   // (8, 512, 512) fp32

    unsigned short* T   = (unsigned short*)d_ws;                 // 1 MB bf16
    float*          Nrm = (float*)((char*)d_ws + (1 << 20));     // 16 KB fp32

    proj_rows<<<256, 512, 0, stream>>>(batch, proj, T, Nrm);
    dist_mfma<<<512, 256, 0, stream>>>(T, Nrm, out);
}